// Round 17
// baseline (499.500 us; speedup 1.0000x reference)
//
#include <hip/hip_runtime.h>
#include <hip/hip_bf16.h>

// Elman RNN, persistent kernel v14 = r16 (406us best) + barrier2 removal:
//  per-wave flags (each in OWN 128B line — r14's packed lines were the real
//  bug: 64 writers + 64 pollers on 2 lines/group/step) + double-buffered red.
// h_t = tanh([h_{t-1} | x_t] @ [Wh|Wi]^T + (Wh_b+Wi_b)); out = h_T @ Wo^T + Wo_b
// T=128, B=512, E=256, H=1024, O=256.
//
// Geometry: 32 groups x 16 rows x 8 blocks (128 cols), 256 blocks, 1/CU,
// 8 waves; wave wv owns k-slice [wv*128,+128); wave w's epilogue owns rows
// {2w, 2w+1} (x 128 cols) -> flag[g][p][w] = "those rows of h_t visible".
// Consumer wave wv needs all 16 rows of producer block wv -> polls its 8
// wave-flags (8 parallel loads, min).
//
// Race-freedom without barrier2:
//  red: double-buffered by t&1; wave u's step-t reads of red[t&1] precede its
//  barrier1(t+1); any wave's step-t+2 writes to red[t&1] follow barrier1(t+2)
//  >= barrier1(t+1). Race-free via barrier1 alone.
//  h-slot overwrite: block p's epilogue store at step t follows barrier1(t),
//  which joins 8 waves that each verified a DISTINCT producer block's 8
//  wave-flags >= t (i.e. that block finished step t-1 = finished reading
//  h_{t-2}, the slot being overwritten). Union = whole group.
//
// Measured laws: r9/10/11 (1 block/CU lockstep), r2 (no RELEASE atomics),
// r4/5/9/13/15 (asm sc0 sc1 for h+flags), r6 (rule-#18 fence), r7/8 (no
// compiler AGENT/SYSTEM atomics), r15 (direct A-frags, conflicts 0),
// r16 (one 128B line per flag; counted vmcnt drains).

#define T_ 128
#define B_ 512
#define E_ 256
#define H_ 1024
#define O_ 256
#define RG 16            // rows per group
#define HB (B_ * H_)     // elems per h slot (1 MB bf16)

typedef __bf16 bf16x8 __attribute__((ext_vector_type(8)));
typedef float  f32x4  __attribute__((ext_vector_type(4)));
typedef unsigned int u32x2 __attribute__((ext_vector_type(2)));
typedef unsigned int u32x4 __attribute__((ext_vector_type(4)));

static __device__ __forceinline__ unsigned short f2bf(float f) {
  unsigned u = __float_as_uint(f);
  u += 0x7fff + ((u >> 16) & 1);  // RNE
  return (unsigned short)(u >> 16);
}
static __device__ __forceinline__ unsigned pk2(float a, float b) {
  return (unsigned)f2bf(a) | ((unsigned)f2bf(b) << 16);
}
static __device__ __forceinline__ bf16x8 cvt8(const float* p) {
  float4 f0 = reinterpret_cast<const float4*>(p)[0];
  float4 f1 = reinterpret_cast<const float4*>(p)[1];
  union { u32x4 u; bf16x8 v; } r;
  r.u = (u32x4){pk2(f0.x, f0.y), pk2(f0.z, f0.w), pk2(f1.x, f1.y), pk2(f1.z, f1.w)};
  return r.v;
}
// tanh(x) = 1 - 2/(exp2(2*log2e*x)+1)
static __device__ __forceinline__ float fast_tanh(float x) {
  float e = __builtin_amdgcn_exp2f(x * 2.8853900817779268f);
  return 1.f - 2.f / (e + 1.f);
}

// Poll 8 wave-flags, each on its OWN 128B line (fl + w*32 words), until all
// >= tgt. 8 loads issue in parallel; vmcnt(0) + rule-#18 fence; min-reduce.
// The internal vmcnt(0) also drains anything issued before the call (xa).
static __device__ __forceinline__ void poll8L(const unsigned* fl, unsigned tgt) {
  for (;;) {
    unsigned f0, f1, f2, f3, f4, f5, f6, f7;
    asm volatile("global_load_dword %0, %1, off sc0 sc1" : "=v"(f0) : "v"(fl) : "memory");
    asm volatile("global_load_dword %0, %1, off sc0 sc1" : "=v"(f1) : "v"(fl + 32) : "memory");
    asm volatile("global_load_dword %0, %1, off sc0 sc1" : "=v"(f2) : "v"(fl + 64) : "memory");
    asm volatile("global_load_dword %0, %1, off sc0 sc1" : "=v"(f3) : "v"(fl + 96) : "memory");
    asm volatile("global_load_dword %0, %1, off sc0 sc1" : "=v"(f4) : "v"(fl + 128) : "memory");
    asm volatile("global_load_dword %0, %1, off sc0 sc1" : "=v"(f5) : "v"(fl + 160) : "memory");
    asm volatile("global_load_dword %0, %1, off sc0 sc1" : "=v"(f6) : "v"(fl + 192) : "memory");
    asm volatile("global_load_dword %0, %1, off sc0 sc1" : "=v"(f7) : "v"(fl + 224) : "memory");
    asm volatile("s_waitcnt vmcnt(0)" ::: "memory");
    __builtin_amdgcn_sched_barrier(0);  // rule #18 fence
    unsigned m = min(min(min(f0, f1), min(f2, f3)),
                     min(min(f4, f5), min(f6, f7)));
    if (m >= tgt) return;
    __builtin_amdgcn_s_sleep(1);
  }
}

// ---------------------------------------------------------------------------
__global__ void prep_kernel(const float* __restrict__ seq,
                            unsigned short* __restrict__ seq_bf,
                            unsigned* __restrict__ flags) {
  size_t idx = (size_t)blockIdx.x * blockDim.x + threadIdx.x;
  size_t stride = (size_t)gridDim.x * blockDim.x;
  const size_t nchunk = (size_t)T_ * B_ * E_ / 8;
  for (size_t i = idx; i < nchunk; i += stride) {
    union { bf16x8 v; u32x4 u; } r;
    r.v = cvt8(seq + i * 8);
    *reinterpret_cast<u32x4*>(seq_bf + i * 8) = r.u;
  }
  if (idx < 65536) {  // 32 groups x 8 producers x 8 waves x 32-word lines
    unsigned z = 0;
    asm volatile("global_store_dword %0, %1, off sc0 sc1"
                 :: "v"(flags + idx), "v"(z) : "memory");
  }
}

// ---------------------------------------------------------------------------
__global__ __launch_bounds__(512, 2) void rnn_fused(
    const unsigned short* __restrict__ seq_bf, const float* __restrict__ Wh_w,
    const float* __restrict__ Wh_b, const float* __restrict__ Wi_w,
    const float* __restrict__ Wi_b, const float* __restrict__ Wo_w,
    const float* __restrict__ Wo_b,
    unsigned short* __restrict__ hbuf, unsigned* __restrict__ flags,
    float* __restrict__ out) {
  __shared__ __align__(16) float red[2][8][RG][132];  // 132 KB, double-buffered

  const int tid = threadIdx.x;
  const int bid = blockIdx.x;
  // group g: 8 blocks at bids {g, g+32, ...} -> all == g (mod 8): same XCD.
  const int g = bid & 31, p = bid >> 5;   // group 0..31, producer-index 0..7
  const int R0 = g * RG, C0 = p * 128;
  const int lane = tid & 63, wv = tid >> 6;   // wv = k-slice index 0..7
  const int l15 = lane & 15, k4 = lane >> 4;  // frag coords: row=l15, kchunk+=k4

  // ---- prologue: weight fragments -> registers for all 128 steps
  bf16x8 bh[8][4];  // Wh[C0+nn*16+l15][wv*128 + (ks*4+k4)*8 ..+8]
#pragma unroll
  for (int nn = 0; nn < 8; ++nn) {
    const float* wp = Wh_w + (size_t)(C0 + nn * 16 + l15) * H_ + wv * 128 + k4 * 8;
#pragma unroll
    for (int ks = 0; ks < 4; ++ks) bh[nn][ks] = cvt8(wp + ks * 32);
  }
  bf16x8 wif[8];    // Wi[C0+nn*16+l15][wv*32 + k4*8 ..+8]
#pragma unroll
  for (int nn = 0; nn < 8; ++nn)
    wif[nn] = cvt8(Wi_w + (size_t)(C0 + nn * 16 + l15) * E_ + wv * 32 + k4 * 8);

  // epilogue mapping (r13/r16): thread -> (erow, cols ec..ec+3); wave w owns
  // rows {2w, 2w+1} -> per-wave flag covers exactly those rows.
  const int erow = tid >> 5, ec = (tid & 31) * 4;
  f32x4 bias4;
  {
    f32x4 b1 = *reinterpret_cast<const f32x4*>(Wh_b + C0 + ec);
    f32x4 b2 = *reinterpret_cast<const f32x4*>(Wi_b + C0 + ec);
    bias4 = b1 + b2;
  }
  // flags: line index (g*64 + p*8 + w), 32 words (128B) per line
  const unsigned* wvfl = flags + (size_t)(g * 64 + wv * 8) * 32;  // producer wv's 8 lines
  unsigned* myfl = flags + (size_t)(g * 64 + p * 8 + wv) * 32;    // own wave flag
  const size_t hoff_b = ((size_t)(R0 + erow) * H_ + C0 + ec) * 2;  // bytes
  // A-frag base bytes within a slot: row R0+l15, col wv*128 + k4*8
  const size_t afr_b = (size_t)(R0 + l15) * 2048 + wv * 256 + k4 * 16;

  for (int t = 0; t < T_; ++t) {
    f32x4 acc[8];
#pragma unroll
    for (int nn = 0; nn < 8; ++nn) acc[nn] = (f32x4){0.f, 0.f, 0.f, 0.f};
    // ---- issue xa as ASM load (drained by poll8L's vmcnt(0))
    union { u32x4 u; bf16x8 v; } xa;
    {
      const unsigned char* xp = (const unsigned char*)seq_bf +
          (((size_t)t * B_ + R0 + l15) * E_ + wv * 32 + k4 * 8) * 2;
      asm volatile("global_load_dwordx4 %0, %1, off"
                   : "=v"(xa.u) : "v"(xp) : "memory");
    }
    u32x4 a0, a1, a2, a3;
    if (t > 0) {
      poll8L(wvfl, (unsigned)t);  // producer block wv fully posted step t-1
      // ---- issue direct-global A-frags (16 rows x 64B per instr, coalesced)
      const unsigned char* ab =
          (const unsigned char*)hbuf + (size_t)((t - 1) & 1) * (HB * 2) + afr_b;
      asm volatile("global_load_dwordx4 %0, %1, off sc0 sc1"
                   : "=v"(a0) : "v"(ab) : "memory");
      asm volatile("global_load_dwordx4 %0, %1, off sc0 sc1"
                   : "=v"(a1) : "v"(ab + 64) : "memory");
      asm volatile("global_load_dwordx4 %0, %1, off sc0 sc1"
                   : "=v"(a2) : "v"(ab + 128) : "memory");
      asm volatile("global_load_dwordx4 %0, %1, off sc0 sc1"
                   : "=v"(a3) : "v"(ab + 192) : "memory");
    } else {
      asm volatile("s_waitcnt vmcnt(0)" ::: "memory");  // xa ready (t==0 path)
      __builtin_amdgcn_sched_barrier(0);
    }
    // ---- all 8 x-MFMAs overlap the a-frag loads in flight
#pragma unroll
    for (int nn = 0; nn < 8; ++nn)
      acc[nn] = __builtin_amdgcn_mfma_f32_16x16x32_bf16(xa.v, wif[nn], acc[nn], 0, 0, 0);
    if (t > 0) {
      // ---- counted drains: consume each a-frag as it lands (T4 pattern)
      union { u32x4 u; bf16x8 v; } af;
#define RNN_HMF(N, KS, AV)                                                       \
      asm volatile("s_waitcnt vmcnt(" #N ")" ::: "memory");                      \
      __builtin_amdgcn_sched_barrier(0);  /* rule #18 */                         \
      af.u = AV;                                                                 \
      _Pragma("unroll")                                                          \
      for (int nn = 0; nn < 8; ++nn)                                             \
        acc[nn] = __builtin_amdgcn_mfma_f32_16x16x32_bf16(af.v, bh[nn][KS],      \
                                                          acc[nn], 0, 0, 0);
      RNN_HMF(3, 0, a0) RNN_HMF(2, 1, a1) RNN_HMF(1, 2, a2) RNN_HMF(0, 3, a3)
#undef RNN_HMF
    }
    // ---- k-split partials -> red[t&1] (C layout: col=l15, row=k4*4+r)
#pragma unroll
    for (int nn = 0; nn < 8; ++nn)
#pragma unroll
      for (int r = 0; r < 4; ++r)
        red[t & 1][wv][k4 * 4 + r][nn * 16 + l15] = acc[nn][r];
    __syncthreads();  // barrier 1: partials in (also the skew reset)
    // ---- per-thread epilogue: 8-source reduce, bias, tanh, 8B store
    {
      f32x4 v = *reinterpret_cast<const f32x4*>(&red[t & 1][0][erow][ec]);
#pragma unroll
      for (int s = 1; s < 8; ++s)
        v += *reinterpret_cast<const f32x4*>(&red[t & 1][s][erow][ec]);
      v += bias4;
      u32x2 pv = {pk2(fast_tanh(v[0]), fast_tanh(v[1])),
                  pk2(fast_tanh(v[2]), fast_tanh(v[3]))};
      const unsigned char* dst =
          (const unsigned char*)hbuf + (size_t)(t & 1) * (HB * 2) + hoff_b;
      asm volatile("global_store_dwordx2 %0, %1, off sc0 sc1"
                   :: "v"(dst), "v"(pv) : "memory");
    }
    // ---- per-wave drain + flag (NO barrier2): wave's rows are visible
    asm volatile("s_waitcnt vmcnt(0)" ::: "memory");
    if (lane == 0) {
      unsigned fv = (unsigned)(t + 1);
      asm volatile("global_store_dword %0, %1, off sc0 sc1"
                   :: "v"(myfl), "v"(fv) : "memory");
    }
  }

  // ---- final GEMM: out = h_T @ Wo^T + Wo_b (blocks p<2 cover 512x256, fp32)
  if (p >= 2) return;
  {
    poll8L(wvfl, (unsigned)T_);
    const unsigned char* ab =
        (const unsigned char*)hbuf + (size_t)((T_ - 1) & 1) * (HB * 2) + afr_b;
    u32x4 a0, a1, a2, a3;
    asm volatile("global_load_dwordx4 %0, %1, off sc0 sc1" : "=v"(a0) : "v"(ab) : "memory");
    asm volatile("global_load_dwordx4 %0, %1, off sc0 sc1" : "=v"(a1) : "v"(ab + 64) : "memory");
    asm volatile("global_load_dwordx4 %0, %1, off sc0 sc1" : "=v"(a2) : "v"(ab + 128) : "memory");
    asm volatile("global_load_dwordx4 %0, %1, off sc0 sc1" : "=v"(a3) : "v"(ab + 192) : "memory");
    asm volatile("s_waitcnt vmcnt(0)" ::: "memory");
    __builtin_amdgcn_sched_barrier(0);
    f32x4 acc[8];
#pragma unroll
    for (int nn = 0; nn < 8; ++nn) acc[nn] = (f32x4){0.f, 0.f, 0.f, 0.f};
    union { u32x4 u; bf16x8 v; } af;
#define RNN_OMF(KS, AV)                                                          \
    af.u = AV;                                                                   \
    _Pragma("unroll")                                                            \
    for (int nn = 0; nn < 8; ++nn) {                                             \
      bf16x8 b = cvt8(Wo_w + (size_t)(C0 + nn * 16 + l15) * H_ +                 \
                      wv * 128 + (KS) * 32 + k4 * 8);                            \
      acc[nn] = __builtin_amdgcn_mfma_f32_16x16x32_bf16(af.v, b, acc[nn], 0, 0, 0); \
    }
    RNN_OMF(0, a0) RNN_OMF(1, a1) RNN_OMF(2, a2) RNN_OMF(3, a3)
#undef RNN_OMF
#pragma unroll
    for (int nn = 0; nn < 8; ++nn)
#pragma unroll
      for (int r = 0; r < 4; ++r)
        red[0][wv][k4 * 4 + r][nn * 16 + l15] = acc[nn][r];
    __syncthreads();
    {
      f32x4 v = *reinterpret_cast<const f32x4*>(&red[0][0][erow][ec]);
#pragma unroll
      for (int s = 1; s < 8; ++s)
        v += *reinterpret_cast<const f32x4*>(&red[0][s][erow][ec]);
      v += *reinterpret_cast<const f32x4*>(Wo_b + C0 + ec);
      *reinterpret_cast<f32x4*>(out + (size_t)(R0 + erow) * O_ + C0 + ec) = v;
    }
  }
}

// ---------------------------------------------------------------------------
extern "C" void kernel_launch(void* const* d_in, const int* in_sizes, int n_in,
                              void* d_out, int out_size, void* d_ws, size_t ws_size,
                              hipStream_t stream) {
  const float* seq  = (const float*)d_in[0];
  const float* Wh_w = (const float*)d_in[1];
  const float* Wh_b = (const float*)d_in[2];
  const float* Wi_w = (const float*)d_in[3];
  const float* Wi_b = (const float*)d_in[4];
  const float* Wo_w = (const float*)d_in[5];
  const float* Wo_b = (const float*)d_in[6];

  char* ws = (char*)d_ws;
  unsigned short* hbuf   = (unsigned short*)ws; ws += (size_t)2 * HB * 2;  // 2 MB
  unsigned*       flags  = (unsigned*)ws;       ws += 262144;              // 2048 x 128B
  unsigned short* seq_bf = (unsigned short*)ws;                            // 32 MB

  prep_kernel<<<2048, 256, 0, stream>>>(seq, seq_bf, flags);
  rnn_fused<<<256, 512, 0, stream>>>(seq_bf, Wh_w, Wh_b, Wi_w, Wi_b, Wo_w, Wo_b,
                                     hbuf, flags, (float*)d_out);
}

// Round 18
// 420.406 us; speedup vs baseline: 1.1881x; 1.1881x over previous
//
#include <hip/hip_runtime.h>
#include <hip/hip_bf16.h>

// Elman RNN, persistent kernel v15 = r16 (406us best) + two critical-path cuts:
//  (1) barrier2 -> LDS completion counter (8th wave posts block flag; other
//      waves proceed immediately); red[] double-buffered so barrier1 alone
//      separates its read/write epochs.
//  (2) cross-step xa pipelining: next step's seq load issues right after the
//      epilogue store; vmcnt(1) drains stores only; poll1's vmcnt(0) lands xa.
// h_t = tanh([h_{t-1} | x_t] @ [Wh|Wi]^T + (Wh_b+Wi_b)); out = h_T @ Wo^T + Wo_b
// T=128, B=512, E=256, H=1024, O=256.
//
// Geometry (r13..r16): 32 groups x 16 rows x 8 blocks (128 cols), 256 blocks,
// 1/CU, 8 waves; wave wv owns k-slice [wv*128,+128); wave wv polls producer-
// block wv's single block flag (one 128B line per (g,p) — r16/r17: flag-line
// sharing AND per-wave flag fan-out both measurably hurt; block-flag + own
// line is the optimum).
//
// Race-freedom:
//  red: double-buffered by t&1. Wave V's step-t reads of red[t&1] precede V's
//  barrier1(t+1); any wave U's step-t+2 writes of red[t&1] follow U's
//  barrier1(t+1) participation. barrier1 alone orders them.
//  cnt: double-buffered by t&1; poster resets cnt[t&1] before its
//  barrier1(t+1); next adds to that buffer happen after barrier1(t+2).
//  flag: posted by the 8th wave whose atomicAdd followed its own vmcnt store
//  drain -> flag==t+1 certifies ALL 8 waves' h stores acked at L2.
//  h-slot overwrite: block p's epilogue store at step t follows barrier1(t),
//  joining 8 waves that each polled a DISTINCT producer flag >= t; flag[j]>=t
//  means block j's waves all drained their step-(t-1) a-frag reads of slot
//  (t-2)&1 (counted vmcnt before h-MFMAs precede epilogue). Union = group.
//
// Protocol laws (measured r2..r17): asm sc0 sc1 for h+flag traffic; explicit
// s_waitcnt only; sched_barrier(0) after any waitcnt with register-only
// consumers (rule #18); no compiler AGENT/SYSTEM atomics on the hot path;
// 1 block/CU lockstep; block-granular flags on private 128B lines.

#define T_ 128
#define B_ 512
#define E_ 256
#define H_ 1024
#define O_ 256
#define RG 16            // rows per group
#define HB (B_ * H_)     // elems per h slot (1 MB bf16)

typedef __bf16 bf16x8 __attribute__((ext_vector_type(8)));
typedef float  f32x4  __attribute__((ext_vector_type(4)));
typedef unsigned int u32x2 __attribute__((ext_vector_type(2)));
typedef unsigned int u32x4 __attribute__((ext_vector_type(4)));

static __device__ __forceinline__ unsigned short f2bf(float f) {
  unsigned u = __float_as_uint(f);
  u += 0x7fff + ((u >> 16) & 1);  // RNE
  return (unsigned short)(u >> 16);
}
static __device__ __forceinline__ unsigned pk2(float a, float b) {
  return (unsigned)f2bf(a) | ((unsigned)f2bf(b) << 16);
}
static __device__ __forceinline__ bf16x8 cvt8(const float* p) {
  float4 f0 = reinterpret_cast<const float4*>(p)[0];
  float4 f1 = reinterpret_cast<const float4*>(p)[1];
  union { u32x4 u; bf16x8 v; } r;
  r.u = (u32x4){pk2(f0.x, f0.y), pk2(f0.z, f0.w), pk2(f1.x, f1.y), pk2(f1.z, f1.w)};
  return r.v;
}
// tanh(x) = 1 - 2/(exp2(2*log2e*x)+1)
static __device__ __forceinline__ float fast_tanh(float x) {
  float e = __builtin_amdgcn_exp2f(x * 2.8853900817779268f);
  return 1.f - 2.f / (e + 1.f);
}

// Poll ONE flag word (own 128B line) + rule-#18 fence. Its vmcnt(0) also
// lands the cross-step xa load issued before the call.
static __device__ __forceinline__ void poll1(const unsigned* fl, unsigned tgt) {
  for (;;) {
    unsigned a;
    asm volatile("global_load_dword %0, %1, off sc0 sc1"
                 : "=v"(a) : "v"(fl) : "memory");
    asm volatile("s_waitcnt vmcnt(0)" ::: "memory");
    __builtin_amdgcn_sched_barrier(0);  // rule #18 fence
    if (a >= tgt) return;
    __builtin_amdgcn_s_sleep(1);
  }
}

// ---------------------------------------------------------------------------
__global__ void prep_kernel(const float* __restrict__ seq,
                            unsigned short* __restrict__ seq_bf,
                            unsigned* __restrict__ flags) {
  size_t idx = (size_t)blockIdx.x * blockDim.x + threadIdx.x;
  size_t stride = (size_t)gridDim.x * blockDim.x;
  const size_t nchunk = (size_t)T_ * B_ * E_ / 8;
  for (size_t i = idx; i < nchunk; i += stride) {
    union { bf16x8 v; u32x4 u; } r;
    r.v = cvt8(seq + i * 8);
    *reinterpret_cast<u32x4*>(seq_bf + i * 8) = r.u;
  }
  if (idx < 8192) {  // 32 groups x 8 producers x 32-word (128B) lines
    unsigned z = 0;
    asm volatile("global_store_dword %0, %1, off sc0 sc1"
                 :: "v"(flags + idx), "v"(z) : "memory");
  }
}

// ---------------------------------------------------------------------------
__global__ __launch_bounds__(512, 2) void rnn_fused(
    const unsigned short* __restrict__ seq_bf, const float* __restrict__ Wh_w,
    const float* __restrict__ Wh_b, const float* __restrict__ Wi_w,
    const float* __restrict__ Wi_b, const float* __restrict__ Wo_w,
    const float* __restrict__ Wo_b,
    unsigned short* __restrict__ hbuf, unsigned* __restrict__ flags,
    float* __restrict__ out) {
  __shared__ __align__(16) float red[2][8][RG][132];  // 132 KB, double-buffered
  __shared__ unsigned cnt[2];                          // wave-completion counters

  const int tid = threadIdx.x;
  const int bid = blockIdx.x;
  // group g: 8 blocks at bids {g, g+32, ...} -> all == g (mod 8): same XCD.
  const int g = bid & 31, p = bid >> 5;   // group 0..31, producer-index 0..7
  const int R0 = g * RG, C0 = p * 128;
  const int lane = tid & 63, wv = tid >> 6;   // wv = k-slice index 0..7
  const int l15 = lane & 15, k4 = lane >> 4;  // frag coords: row=l15, kchunk+=k4

  if (tid == 0) { cnt[0] = 0; cnt[1] = 0; }

  // ---- prologue: weight fragments -> registers for all 128 steps
  bf16x8 bh[8][4];  // Wh[C0+nn*16+l15][wv*128 + (ks*4+k4)*8 ..+8]
#pragma unroll
  for (int nn = 0; nn < 8; ++nn) {
    const float* wp = Wh_w + (size_t)(C0 + nn * 16 + l15) * H_ + wv * 128 + k4 * 8;
#pragma unroll
    for (int ks = 0; ks < 4; ++ks) bh[nn][ks] = cvt8(wp + ks * 32);
  }
  bf16x8 wif[8];    // Wi[C0+nn*16+l15][wv*32 + k4*8 ..+8]
#pragma unroll
  for (int nn = 0; nn < 8; ++nn)
    wif[nn] = cvt8(Wi_w + (size_t)(C0 + nn * 16 + l15) * E_ + wv * 32 + k4 * 8);

  // epilogue mapping (r13/r16): thread -> (erow, cols ec..ec+3)
  const int erow = tid >> 5, ec = (tid & 31) * 4;
  f32x4 bias4;
  {
    f32x4 b1 = *reinterpret_cast<const f32x4*>(Wh_b + C0 + ec);
    f32x4 b2 = *reinterpret_cast<const f32x4*>(Wi_b + C0 + ec);
    bias4 = b1 + b2;
  }
  // flags: one 128B line per (group, producer): word index g*256 + p*32
  const unsigned* wvfl = flags + g * 256 + wv * 32;  // this wave's producer line
  unsigned* myfl = flags + g * 256 + p * 32;
  const size_t hoff_b = ((size_t)(R0 + erow) * H_ + C0 + ec) * 2;  // bytes
  // A-frag base bytes within a slot: row R0+l15, col wv*128 + k4*8
  const size_t afr_b = (size_t)(R0 + l15) * 2048 + wv * 256 + k4 * 16;
  // per-thread seq address stride: one step = B_*E_ elems
  const unsigned char* xp0 = (const unsigned char*)seq_bf +
      (((size_t)R0 + l15) * E_ + wv * 32 + k4 * 8) * 2;

  // ---- issue xa for t=0 (landed by the explicit vmcnt in the t==0 path)
  union { u32x4 u; bf16x8 v; } xa;
  asm volatile("global_load_dwordx4 %0, %1, off"
               : "=v"(xa.u) : "v"(xp0) : "memory");

  for (int t = 0; t < T_; ++t) {
    f32x4 acc[8];
#pragma unroll
    for (int nn = 0; nn < 8; ++nn) acc[nn] = (f32x4){0.f, 0.f, 0.f, 0.f};
    u32x4 a0, a1, a2, a3;
    if (t > 0) {
      poll1(wvfl, (unsigned)t);  // vmcnt(0)+fence inside: xa is now resident
      // ---- issue direct-global A-frags (16 rows x 64B per instr, coalesced)
      const unsigned char* ab =
          (const unsigned char*)hbuf + (size_t)((t - 1) & 1) * (HB * 2) + afr_b;
      asm volatile("global_load_dwordx4 %0, %1, off sc0 sc1"
                   : "=v"(a0) : "v"(ab) : "memory");
      asm volatile("global_load_dwordx4 %0, %1, off sc0 sc1"
                   : "=v"(a1) : "v"(ab + 64) : "memory");
      asm volatile("global_load_dwordx4 %0, %1, off sc0 sc1"
                   : "=v"(a2) : "v"(ab + 128) : "memory");
      asm volatile("global_load_dwordx4 %0, %1, off sc0 sc1"
                   : "=v"(a3) : "v"(ab + 192) : "memory");
    } else {
      asm volatile("s_waitcnt vmcnt(0)" ::: "memory");  // xa ready (t==0 path)
      __builtin_amdgcn_sched_barrier(0);
    }
    // ---- all 8 x-MFMAs overlap the a-frag loads in flight
#pragma unroll
    for (int nn = 0; nn < 8; ++nn)
      acc[nn] = __builtin_amdgcn_mfma_f32_16x16x32_bf16(xa.v, wif[nn], acc[nn], 0, 0, 0);
    if (t > 0) {
      // ---- counted drains: consume each a-frag as it lands (T4 pattern)
      union { u32x4 u; bf16x8 v; } af;
#define RNN_HMF(N, KS, AV)                                                       \
      asm volatile("s_waitcnt vmcnt(" #N ")" ::: "memory");                      \
      __builtin_amdgcn_sched_barrier(0);  /* rule #18 */                         \
      af.u = AV;                                                                 \
      _Pragma("unroll")                                                          \
      for (int nn = 0; nn < 8; ++nn)                                             \
        acc[nn] = __builtin_amdgcn_mfma_f32_16x16x32_bf16(af.v, bh[nn][KS],      \
                                                          acc[nn], 0, 0, 0);
      RNN_HMF(3, 0, a0) RNN_HMF(2, 1, a1) RNN_HMF(1, 2, a2) RNN_HMF(0, 3, a3)
#undef RNN_HMF
    }
    // ---- k-split partials -> red[t&1] (C layout: col=l15, row=k4*4+r)
#pragma unroll
    for (int nn = 0; nn < 8; ++nn)
#pragma unroll
      for (int r = 0; r < 4; ++r)
        red[t & 1][wv][k4 * 4 + r][nn * 16 + l15] = acc[nn][r];
    __syncthreads();  // barrier 1 (the only barrier; also the skew reset)
    // ---- epilogue: 8-source reduce, bias, tanh, 8B store
    {
      f32x4 v = *reinterpret_cast<const f32x4*>(&red[t & 1][0][erow][ec]);
#pragma unroll
      for (int s = 1; s < 8; ++s)
        v += *reinterpret_cast<const f32x4*>(&red[t & 1][s][erow][ec]);
      v += bias4;
      u32x2 pv = {pk2(fast_tanh(v[0]), fast_tanh(v[1])),
                  pk2(fast_tanh(v[2]), fast_tanh(v[3]))};
      const unsigned char* dst =
          (const unsigned char*)hbuf + (size_t)(t & 1) * (HB * 2) + hoff_b;
      asm volatile("global_store_dwordx2 %0, %1, off sc0 sc1"
                   :: "v"(dst), "v"(pv) : "memory");
    }
    // ---- issue NEXT step's xa (after the store!), then drain stores only
    {
      int tn = (t + 1 < T_) ? (t + 1) : t;  // clamp: last iter reloads (unused)
      const unsigned char* xp = xp0 + (size_t)tn * (B_ * E_ * 2);
      asm volatile("global_load_dwordx4 %0, %1, off"
                   : "=v"(xa.u) : "v"(xp) : "memory");
    }
    asm volatile("s_waitcnt vmcnt(1)" ::: "memory");  // h stores acked; xa flies
    // ---- wave-completion counter replaces barrier2; 8th wave posts the flag
    if (lane == 0) {
      unsigned old = atomicAdd(&cnt[t & 1], 1u);
      if (old == 7u) {
        unsigned fv = (unsigned)(t + 1);
        asm volatile("global_store_dword %0, %1, off sc0 sc1"
                     :: "v"(myfl), "v"(fv) : "memory");
        cnt[t & 1] = 0;  // reset; ordered vs t+2 adds by barrier1(t+1)
      }
    }
  }

  // ---- final GEMM: out = h_T @ Wo^T + Wo_b (blocks p<2 cover 512x256, fp32)
  if (p >= 2) return;
  {
    poll1(wvfl, (unsigned)T_);
    const unsigned char* ab =
        (const unsigned char*)hbuf + (size_t)((T_ - 1) & 1) * (HB * 2) + afr_b;
    u32x4 a0, a1, a2, a3;
    asm volatile("global_load_dwordx4 %0, %1, off sc0 sc1" : "=v"(a0) : "v"(ab) : "memory");
    asm volatile("global_load_dwordx4 %0, %1, off sc0 sc1" : "=v"(a1) : "v"(ab + 64) : "memory");
    asm volatile("global_load_dwordx4 %0, %1, off sc0 sc1" : "=v"(a2) : "v"(ab + 128) : "memory");
    asm volatile("global_load_dwordx4 %0, %1, off sc0 sc1" : "=v"(a3) : "v"(ab + 192) : "memory");
    asm volatile("s_waitcnt vmcnt(0)" ::: "memory");
    __builtin_amdgcn_sched_barrier(0);
    f32x4 acc[8];
#pragma unroll
    for (int nn = 0; nn < 8; ++nn) acc[nn] = (f32x4){0.f, 0.f, 0.f, 0.f};
    union { u32x4 u; bf16x8 v; } af;
#define RNN_OMF(KS, AV)                                                          \
    af.u = AV;                                                                   \
    _Pragma("unroll")                                                            \
    for (int nn = 0; nn < 8; ++nn) {                                             \
      bf16x8 b = cvt8(Wo_w + (size_t)(C0 + nn * 16 + l15) * H_ +                 \
                      wv * 128 + (KS) * 32 + k4 * 8);                            \
      acc[nn] = __builtin_amdgcn_mfma_f32_16x16x32_bf16(af.v, b, acc[nn], 0, 0, 0); \
    }
    RNN_OMF(0, a0) RNN_OMF(1, a1) RNN_OMF(2, a2) RNN_OMF(3, a3)
#undef RNN_OMF
#pragma unroll
    for (int nn = 0; nn < 8; ++nn)
#pragma unroll
      for (int r = 0; r < 4; ++r)
        red[0][wv][k4 * 4 + r][nn * 16 + l15] = acc[nn][r];
    __syncthreads();
    {
      f32x4 v = *reinterpret_cast<const f32x4*>(&red[0][0][erow][ec]);
#pragma unroll
      for (int s = 1; s < 8; ++s)
        v += *reinterpret_cast<const f32x4*>(&red[0][s][erow][ec]);
      v += *reinterpret_cast<const f32x4*>(Wo_b + C0 + ec);
      *reinterpret_cast<f32x4*>(out + (size_t)(R0 + erow) * O_ + C0 + ec) = v;
    }
  }
}

// ---------------------------------------------------------------------------
extern "C" void kernel_launch(void* const* d_in, const int* in_sizes, int n_in,
                              void* d_out, int out_size, void* d_ws, size_t ws_size,
                              hipStream_t stream) {
  const float* seq  = (const float*)d_in[0];
  const float* Wh_w = (const float*)d_in[1];
  const float* Wh_b = (const float*)d_in[2];
  const float* Wi_w = (const float*)d_in[3];
  const float* Wi_b = (const float*)d_in[4];
  const float* Wo_w = (const float*)d_in[5];
  const float* Wo_b = (const float*)d_in[6];

  char* ws = (char*)d_ws;
  unsigned short* hbuf   = (unsigned short*)ws; ws += (size_t)2 * HB * 2;  // 2 MB
  unsigned*       flags  = (unsigned*)ws;       ws += 32768;               // 32x8x128B
  unsigned short* seq_bf = (unsigned short*)ws;                            // 32 MB

  prep_kernel<<<2048, 256, 0, stream>>>(seq, seq_bf, flags);
  rnn_fused<<<256, 512, 0, stream>>>(seq_bf, Wh_w, Wh_b, Wi_w, Wi_b, Wo_w, Wo_b,
                                     hbuf, flags, (float*)d_out);
}

// Round 19
// 410.428 us; speedup vs baseline: 1.2170x; 1.0243x over previous
//
#include <hip/hip_runtime.h>
#include <hip/hip_bf16.h>

// Elman RNN, persistent kernel v16 = r16 (406us best) + two isolated micro-cuts:
//  (1) next-step xa issued right after the epilogue h-store; stores drained
//      with vmcnt(1) so xa flies through barrier2+flag+poll (poll lands it).
//  (2) hot-spin poll (no s_sleep): L2 load latency already throttles the loop;
//      sleep only added flag-observation lag.
// r18 lesson: barrier2 + tid0-flag BEATS a distributed completion counter
// (8 serialized LDS atomics delay the post; freed waves just spin anyway).
// h_t = tanh([h_{t-1} | x_t] @ [Wh|Wi]^T + (Wh_b+Wi_b)); out = h_T @ Wo^T + Wo_b
// T=128, B=512, E=256, H=1024, O=256.
//
// Geometry (r13..r16): 32 groups x 16 rows x 8 blocks (128 cols), 256 blocks,
// 1/CU, 8 waves; wave wv owns k-slice [wv*128,+128); wave wv polls producer-
// block wv's single block flag on its own 128B line. VGPR wall: bh = cols x
// 4B/thread -> 128 cols/block max -> group of 8 is forced.
//
// Protocol laws (measured r2..r18): asm sc0 sc1 for h+flag traffic (local-L2
// served); explicit s_waitcnt only; sched_barrier(0) after any waitcnt whose
// consumers are register-only (rule #18); no compiler AGENT/SYSTEM atomics on
// the hot path; 1 block/CU lockstep; block-granular flags on private 128B
// lines (r16 vs r17); both barriers kept (r14/r18).
//
// Slot-overwrite safety (r13 proof): block p's epilogue store at step t (slot
// t&1, overwriting h of t-2) follows barrier1(t), which joins 8 waves that
// each polled a DISTINCT producer flag >= t; flag[j] >= t means block j passed
// barrier2(t-1), hence all its a-frag reads of slot (t-2)&1 drained. QED.

#define T_ 128
#define B_ 512
#define E_ 256
#define H_ 1024
#define O_ 256
#define RG 16            // rows per group
#define HB (B_ * H_)     // elems per h slot (1 MB bf16)

typedef __bf16 bf16x8 __attribute__((ext_vector_type(8)));
typedef float  f32x4  __attribute__((ext_vector_type(4)));
typedef unsigned int u32x2 __attribute__((ext_vector_type(2)));
typedef unsigned int u32x4 __attribute__((ext_vector_type(4)));

static __device__ __forceinline__ unsigned short f2bf(float f) {
  unsigned u = __float_as_uint(f);
  u += 0x7fff + ((u >> 16) & 1);  // RNE
  return (unsigned short)(u >> 16);
}
static __device__ __forceinline__ unsigned pk2(float a, float b) {
  return (unsigned)f2bf(a) | ((unsigned)f2bf(b) << 16);
}
static __device__ __forceinline__ bf16x8 cvt8(const float* p) {
  float4 f0 = reinterpret_cast<const float4*>(p)[0];
  float4 f1 = reinterpret_cast<const float4*>(p)[1];
  union { u32x4 u; bf16x8 v; } r;
  r.u = (u32x4){pk2(f0.x, f0.y), pk2(f0.z, f0.w), pk2(f1.x, f1.y), pk2(f1.z, f1.w)};
  return r.v;
}
// tanh(x) = 1 - 2/(exp2(2*log2e*x)+1)
static __device__ __forceinline__ float fast_tanh(float x) {
  float e = __builtin_amdgcn_exp2f(x * 2.8853900817779268f);
  return 1.f - 2.f / (e + 1.f);
}

// Poll ONE flag word (own 128B line) + rule-#18 fence. Hot spin: the sc0sc1
// load's L2 round-trip throttles the loop. Its vmcnt(0) also lands the
// cross-step xa load issued before the call.
static __device__ __forceinline__ void poll1(const unsigned* fl, unsigned tgt) {
  for (;;) {
    unsigned a;
    asm volatile("global_load_dword %0, %1, off sc0 sc1"
                 : "=v"(a) : "v"(fl) : "memory");
    asm volatile("s_waitcnt vmcnt(0)" ::: "memory");
    __builtin_amdgcn_sched_barrier(0);  // rule #18 fence
    if (a >= tgt) return;
  }
}

// ---------------------------------------------------------------------------
__global__ void prep_kernel(const float* __restrict__ seq,
                            unsigned short* __restrict__ seq_bf,
                            unsigned* __restrict__ flags) {
  size_t idx = (size_t)blockIdx.x * blockDim.x + threadIdx.x;
  size_t stride = (size_t)gridDim.x * blockDim.x;
  const size_t nchunk = (size_t)T_ * B_ * E_ / 8;
  for (size_t i = idx; i < nchunk; i += stride) {
    union { bf16x8 v; u32x4 u; } r;
    r.v = cvt8(seq + i * 8);
    *reinterpret_cast<u32x4*>(seq_bf + i * 8) = r.u;
  }
  if (idx < 8192) {  // 32 groups x 8 producers x 32-word (128B) lines
    unsigned z = 0;
    asm volatile("global_store_dword %0, %1, off sc0 sc1"
                 :: "v"(flags + idx), "v"(z) : "memory");
  }
}

// ---------------------------------------------------------------------------
__global__ __launch_bounds__(512, 2) void rnn_fused(
    const unsigned short* __restrict__ seq_bf, const float* __restrict__ Wh_w,
    const float* __restrict__ Wh_b, const float* __restrict__ Wi_w,
    const float* __restrict__ Wi_b, const float* __restrict__ Wo_w,
    const float* __restrict__ Wo_b,
    unsigned short* __restrict__ hbuf, unsigned* __restrict__ flags,
    float* __restrict__ out) {
  __shared__ __align__(16) float red[8][RG][132];  // 67.6 KB k-split partials

  const int tid = threadIdx.x;
  const int bid = blockIdx.x;
  // group g: 8 blocks at bids {g, g+32, ...} -> all == g (mod 8): same XCD.
  const int g = bid & 31, p = bid >> 5;   // group 0..31, producer-index 0..7
  const int R0 = g * RG, C0 = p * 128;
  const int lane = tid & 63, wv = tid >> 6;   // wv = k-slice index 0..7
  const int l15 = lane & 15, k4 = lane >> 4;  // frag coords: row=l15, kchunk+=k4

  // ---- prologue: weight fragments -> registers for all 128 steps
  bf16x8 bh[8][4];  // Wh[C0+nn*16+l15][wv*128 + (ks*4+k4)*8 ..+8]
#pragma unroll
  for (int nn = 0; nn < 8; ++nn) {
    const float* wp = Wh_w + (size_t)(C0 + nn * 16 + l15) * H_ + wv * 128 + k4 * 8;
#pragma unroll
    for (int ks = 0; ks < 4; ++ks) bh[nn][ks] = cvt8(wp + ks * 32);
  }
  bf16x8 wif[8];    // Wi[C0+nn*16+l15][wv*32 + k4*8 ..+8]
#pragma unroll
  for (int nn = 0; nn < 8; ++nn)
    wif[nn] = cvt8(Wi_w + (size_t)(C0 + nn * 16 + l15) * E_ + wv * 32 + k4 * 8);

  // epilogue mapping (r13/r16): thread -> (erow, cols ec..ec+3)
  const int erow = tid >> 5, ec = (tid & 31) * 4;
  f32x4 bias4;
  {
    f32x4 b1 = *reinterpret_cast<const f32x4*>(Wh_b + C0 + ec);
    f32x4 b2 = *reinterpret_cast<const f32x4*>(Wi_b + C0 + ec);
    bias4 = b1 + b2;
  }
  // flags: one 128B line per (group, producer): word index g*256 + p*32
  const unsigned* wvfl = flags + g * 256 + wv * 32;  // this wave's producer line
  unsigned* myfl = flags + g * 256 + p * 32;
  const size_t hoff_b = ((size_t)(R0 + erow) * H_ + C0 + ec) * 2;  // bytes
  // A-frag base bytes within a slot: row R0+l15, col wv*128 + k4*8
  const size_t afr_b = (size_t)(R0 + l15) * 2048 + wv * 256 + k4 * 16;
  // per-thread seq base
  const unsigned char* xp0 = (const unsigned char*)seq_bf +
      (((size_t)R0 + l15) * E_ + wv * 32 + k4 * 8) * 2;

  // ---- issue xa for t=0 (landed by the explicit vmcnt in the t==0 path)
  union { u32x4 u; bf16x8 v; } xa;
  asm volatile("global_load_dwordx4 %0, %1, off"
               : "=v"(xa.u) : "v"(xp0) : "memory");

  for (int t = 0; t < T_; ++t) {
    f32x4 acc[8];
#pragma unroll
    for (int nn = 0; nn < 8; ++nn) acc[nn] = (f32x4){0.f, 0.f, 0.f, 0.f};
    u32x4 a0, a1, a2, a3;
    if (t > 0) {
      poll1(wvfl, (unsigned)t);  // vmcnt(0)+fence inside: xa is now resident
      // ---- issue direct-global A-frags (16 rows x 64B per instr, coalesced)
      const unsigned char* ab =
          (const unsigned char*)hbuf + (size_t)((t - 1) & 1) * (HB * 2) + afr_b;
      asm volatile("global_load_dwordx4 %0, %1, off sc0 sc1"
                   : "=v"(a0) : "v"(ab) : "memory");
      asm volatile("global_load_dwordx4 %0, %1, off sc0 sc1"
                   : "=v"(a1) : "v"(ab + 64) : "memory");
      asm volatile("global_load_dwordx4 %0, %1, off sc0 sc1"
                   : "=v"(a2) : "v"(ab + 128) : "memory");
      asm volatile("global_load_dwordx4 %0, %1, off sc0 sc1"
                   : "=v"(a3) : "v"(ab + 192) : "memory");
    } else {
      asm volatile("s_waitcnt vmcnt(0)" ::: "memory");  // xa ready (t==0 path)
      __builtin_amdgcn_sched_barrier(0);
    }
    // ---- all 8 x-MFMAs overlap the a-frag loads in flight
#pragma unroll
    for (int nn = 0; nn < 8; ++nn)
      acc[nn] = __builtin_amdgcn_mfma_f32_16x16x32_bf16(xa.v, wif[nn], acc[nn], 0, 0, 0);
    if (t > 0) {
      // ---- counted drains: consume each a-frag as it lands (T4 pattern)
      union { u32x4 u; bf16x8 v; } af;
#define RNN_HMF(N, KS, AV)                                                       \
      asm volatile("s_waitcnt vmcnt(" #N ")" ::: "memory");                      \
      __builtin_amdgcn_sched_barrier(0);  /* rule #18 */                         \
      af.u = AV;                                                                 \
      _Pragma("unroll")                                                          \
      for (int nn = 0; nn < 8; ++nn)                                             \
        acc[nn] = __builtin_amdgcn_mfma_f32_16x16x32_bf16(af.v, bh[nn][KS],      \
                                                          acc[nn], 0, 0, 0);
      RNN_HMF(3, 0, a0) RNN_HMF(2, 1, a1) RNN_HMF(1, 2, a2) RNN_HMF(0, 3, a3)
#undef RNN_HMF
    }
    // ---- k-split partials (C layout: col=l15, row=k4*4+r)
#pragma unroll
    for (int nn = 0; nn < 8; ++nn)
#pragma unroll
      for (int r = 0; r < 4; ++r)
        red[wv][k4 * 4 + r][nn * 16 + l15] = acc[nn][r];
    __syncthreads();  // barrier 1: partials in
    // ---- distributed epilogue: 4 cols/thread, 8-source reduce, tanh, 8B store
    {
      f32x4 v = *reinterpret_cast<const f32x4*>(&red[0][erow][ec]);
#pragma unroll
      for (int s = 1; s < 8; ++s)
        v += *reinterpret_cast<const f32x4*>(&red[s][erow][ec]);
      v += bias4;
      u32x2 pv = {pk2(fast_tanh(v[0]), fast_tanh(v[1])),
                  pk2(fast_tanh(v[2]), fast_tanh(v[3]))};
      const unsigned char* dst =
          (const unsigned char*)hbuf + (size_t)(t & 1) * (HB * 2) + hoff_b;
      asm volatile("global_store_dwordx2 %0, %1, off sc0 sc1"
                   :: "v"(dst), "v"(pv) : "memory");
    }
    // ---- issue NEXT step's xa (after the store), drain stores only: xa flies
    {
      int tn = (t + 1 < T_) ? (t + 1) : t;  // clamp: last iter reloads (unused)
      const unsigned char* xp = xp0 + (size_t)tn * (B_ * E_ * 2);
      asm volatile("global_load_dwordx4 %0, %1, off"
                   : "=v"(xa.u) : "v"(xp) : "memory");
    }
    asm volatile("s_waitcnt vmcnt(1)" ::: "memory");  // h stores acked; xa flies
    __syncthreads();  // barrier 2: all waves' stores drained before the flag
    if (tid == 0) {
      unsigned fv = (unsigned)(t + 1);
      asm volatile("global_store_dword %0, %1, off sc0 sc1"
                   :: "v"(myfl), "v"(fv) : "memory");
    }
  }

  // ---- final GEMM: out = h_T @ Wo^T + Wo_b (blocks p<2 cover 512x256, fp32)
  if (p >= 2) return;
  {
    poll1(wvfl, (unsigned)T_);
    const unsigned char* ab =
        (const unsigned char*)hbuf + (size_t)((T_ - 1) & 1) * (HB * 2) + afr_b;
    u32x4 a0, a1, a2, a3;
    asm volatile("global_load_dwordx4 %0, %1, off sc0 sc1" : "=v"(a0) : "v"(ab) : "memory");
    asm volatile("global_load_dwordx4 %0, %1, off sc0 sc1" : "=v"(a1) : "v"(ab + 64) : "memory");
    asm volatile("global_load_dwordx4 %0, %1, off sc0 sc1" : "=v"(a2) : "v"(ab + 128) : "memory");
    asm volatile("global_load_dwordx4 %0, %1, off sc0 sc1" : "=v"(a3) : "v"(ab + 192) : "memory");
    asm volatile("s_waitcnt vmcnt(0)" ::: "memory");
    __builtin_amdgcn_sched_barrier(0);
    f32x4 acc[8];
#pragma unroll
    for (int nn = 0; nn < 8; ++nn) acc[nn] = (f32x4){0.f, 0.f, 0.f, 0.f};
    union { u32x4 u; bf16x8 v; } af;
#define RNN_OMF(KS, AV)                                                          \
    af.u = AV;                                                                   \
    _Pragma("unroll")                                                            \
    for (int nn = 0; nn < 8; ++nn) {                                             \
      bf16x8 b = cvt8(Wo_w + (size_t)(C0 + nn * 16 + l15) * H_ +                 \
                      wv * 128 + (KS) * 32 + k4 * 8);                            \
      acc[nn] = __builtin_amdgcn_mfma_f32_16x16x32_bf16(af.v, b, acc[nn], 0, 0, 0); \
    }
    RNN_OMF(0, a0) RNN_OMF(1, a1) RNN_OMF(2, a2) RNN_OMF(3, a3)
#undef RNN_OMF
#pragma unroll
    for (int nn = 0; nn < 8; ++nn)
#pragma unroll
      for (int r = 0; r < 4; ++r)
        red[wv][k4 * 4 + r][nn * 16 + l15] = acc[nn][r];
    __syncthreads();
    {
      f32x4 v = *reinterpret_cast<const f32x4*>(&red[0][erow][ec]);
#pragma unroll
      for (int s = 1; s < 8; ++s)
        v += *reinterpret_cast<const f32x4*>(&red[s][erow][ec]);
      v += *reinterpret_cast<const f32x4*>(Wo_b + C0 + ec);
      *reinterpret_cast<f32x4*>(out + (size_t)(R0 + erow) * O_ + C0 + ec) = v;
    }
  }
}

// ---------------------------------------------------------------------------
extern "C" void kernel_launch(void* const* d_in, const int* in_sizes, int n_in,
                              void* d_out, int out_size, void* d_ws, size_t ws_size,
                              hipStream_t stream) {
  const float* seq  = (const float*)d_in[0];
  const float* Wh_w = (const float*)d_in[1];
  const float* Wh_b = (const float*)d_in[2];
  const float* Wi_w = (const float*)d_in[3];
  const float* Wi_b = (const float*)d_in[4];
  const float* Wo_w = (const float*)d_in[5];
  const float* Wo_b = (const float*)d_in[6];

  char* ws = (char*)d_ws;
  unsigned short* hbuf   = (unsigned short*)ws; ws += (size_t)2 * HB * 2;  // 2 MB
  unsigned*       flags  = (unsigned*)ws;       ws += 32768;               // 32x8x128B
  unsigned short* seq_bf = (unsigned short*)ws;                            // 32 MB

  prep_kernel<<<2048, 256, 0, stream>>>(seq, seq_bf, flags);
  rnn_fused<<<256, 512, 0, stream>>>(seq_bf, Wh_w, Wh_b, Wi_w, Wi_b, Wo_w, Wo_b,
                                     hbuf, flags, (float*)d_out);
}